// Round 1
// baseline (355.328 us; speedup 1.0000x reference)
//
#include <hip/hip_runtime.h>

#define N_ROWS 8192
#define K_COLS 32000

// One block per row. 256 threads, float4 loads: 8000 float4 per row per stream.
__global__ __launch_bounds__(256) void sce_row_kernel(const float* __restrict__ input,
                                                      const float* __restrict__ target,
                                                      float* __restrict__ row_loss) {
    const int row = blockIdx.x;
    const int tid = threadIdx.x;
    const float4* in4 = reinterpret_cast<const float4*>(input + (size_t)row * K_COLS);
    const float4* tg4 = reinterpret_cast<const float4*>(target + (size_t)row * K_COLS);
    const int n4 = K_COLS / 4;  // 8000

    float s   = 0.f;  // sum exp(x)
    float dot = 0.f;  // sum t*x
    float st  = 0.f;  // sum t
    for (int i = tid; i < n4; i += 256) {
        float4 x = in4[i];
        float4 t = tg4[i];
        s  += __expf(x.x) + __expf(x.y) + __expf(x.z) + __expf(x.w);
        dot = fmaf(t.x, x.x, dot);
        dot = fmaf(t.y, x.y, dot);
        dot = fmaf(t.z, x.z, dot);
        dot = fmaf(t.w, x.w, dot);
        st += t.x + t.y + t.z + t.w;
    }

    // 64-lane wave reduction
    #pragma unroll
    for (int off = 32; off > 0; off >>= 1) {
        s   += __shfl_down(s,   off, 64);
        dot += __shfl_down(dot, off, 64);
        st  += __shfl_down(st,  off, 64);
    }

    __shared__ float sh[3][4];
    const int wid  = tid >> 6;
    const int lane = tid & 63;
    if (lane == 0) { sh[0][wid] = s; sh[1][wid] = dot; sh[2][wid] = st; }
    __syncthreads();
    if (tid == 0) {
        float S = sh[0][0] + sh[0][1] + sh[0][2] + sh[0][3];
        float D = sh[1][0] + sh[1][1] + sh[1][2] + sh[1][3];
        float T = sh[2][0] + sh[2][1] + sh[2][2] + sh[2][3];
        // loss_row = -sum t*(x - log(sum exp)) = T*log(S) - D
        row_loss[row] = T * logf(S) - D;
    }
}

// Single block: deterministic mean over 8192 row losses.
__global__ __launch_bounds__(256) void sce_reduce_kernel(const float* __restrict__ row_loss,
                                                         float* __restrict__ out) {
    const int tid = threadIdx.x;
    const float4* rl4 = reinterpret_cast<const float4*>(row_loss);
    float acc = 0.f;
    for (int i = tid; i < N_ROWS / 4; i += 256) {
        float4 v = rl4[i];
        acc += v.x + v.y + v.z + v.w;
    }
    #pragma unroll
    for (int off = 32; off > 0; off >>= 1) acc += __shfl_down(acc, off, 64);
    __shared__ float sh[4];
    if ((tid & 63) == 0) sh[tid >> 6] = acc;
    __syncthreads();
    if (tid == 0) out[0] = (sh[0] + sh[1] + sh[2] + sh[3]) / (float)N_ROWS;
}

extern "C" void kernel_launch(void* const* d_in, const int* in_sizes, int n_in,
                              void* d_out, int out_size, void* d_ws, size_t ws_size,
                              hipStream_t stream) {
    const float* input  = (const float*)d_in[0];
    const float* target = (const float*)d_in[1];
    float* out      = (float*)d_out;
    float* row_loss = (float*)d_ws;  // 8192 floats = 32 KB scratch

    sce_row_kernel<<<N_ROWS, 256, 0, stream>>>(input, target, row_loss);
    sce_reduce_kernel<<<1, 256, 0, stream>>>(row_loss, out);
}

// Round 3
// 315.526 us; speedup vs baseline: 1.1261x; 1.1261x over previous
//
#include <hip/hip_runtime.h>

#define N_ROWS 8192
#define K_COLS 32000

typedef float f32x4 __attribute__((ext_vector_type(4)));

// One block per row. 256 threads, float4 nontemporal loads.
// 8000 float4 per stream per row = 31 full iterations/thread + 64-wide tail.
__global__ __launch_bounds__(256) void sce_row_kernel(const float* __restrict__ input,
                                                      const float* __restrict__ target,
                                                      float* __restrict__ row_loss) {
    const int row = blockIdx.x;
    const int tid = threadIdx.x;
    const f32x4* in4 = reinterpret_cast<const f32x4*>(input + (size_t)row * K_COLS);
    const f32x4* tg4 = reinterpret_cast<const f32x4*>(target + (size_t)row * K_COLS);
    constexpr int NT   = 256;
    constexpr int n4   = K_COLS / 4;        // 8000
    constexpr int FULL = n4 / NT;           // 31 (covers [0, 7936))
    constexpr int TAIL = n4 - FULL * NT;    // 64

    float s   = 0.f;  // sum exp(x)
    float dot = 0.f;  // sum t*x
    float st  = 0.f;  // sum t

    #pragma unroll 4
    for (int j = 0; j < FULL; ++j) {
        const int i = tid + j * NT;
        f32x4 x = __builtin_nontemporal_load(&in4[i]);
        f32x4 t = __builtin_nontemporal_load(&tg4[i]);
        s  += __expf(x.x) + __expf(x.y) + __expf(x.z) + __expf(x.w);
        dot = fmaf(t.x, x.x, dot);
        dot = fmaf(t.y, x.y, dot);
        dot = fmaf(t.z, x.z, dot);
        dot = fmaf(t.w, x.w, dot);
        st += t.x + t.y + t.z + t.w;
    }
    if (tid < TAIL) {
        const int i = FULL * NT + tid;
        f32x4 x = __builtin_nontemporal_load(&in4[i]);
        f32x4 t = __builtin_nontemporal_load(&tg4[i]);
        s  += __expf(x.x) + __expf(x.y) + __expf(x.z) + __expf(x.w);
        dot = fmaf(t.x, x.x, dot);
        dot = fmaf(t.y, x.y, dot);
        dot = fmaf(t.z, x.z, dot);
        dot = fmaf(t.w, x.w, dot);
        st += t.x + t.y + t.z + t.w;
    }

    // 64-lane wave reduction
    #pragma unroll
    for (int off = 32; off > 0; off >>= 1) {
        s   += __shfl_down(s,   off, 64);
        dot += __shfl_down(dot, off, 64);
        st  += __shfl_down(st,  off, 64);
    }

    __shared__ float sh[3][4];
    const int wid  = tid >> 6;
    const int lane = tid & 63;
    if (lane == 0) { sh[0][wid] = s; sh[1][wid] = dot; sh[2][wid] = st; }
    __syncthreads();
    if (tid == 0) {
        float S = sh[0][0] + sh[0][1] + sh[0][2] + sh[0][3];
        float D = sh[1][0] + sh[1][1] + sh[1][2] + sh[1][3];
        float T = sh[2][0] + sh[2][1] + sh[2][2] + sh[2][3];
        // loss_row = -sum t*(x - log(sum exp)) = T*log(S) - D
        row_loss[row] = T * logf(S) - D;
    }
}

// Single block: deterministic mean over 8192 row losses.
__global__ __launch_bounds__(256) void sce_reduce_kernel(const float* __restrict__ row_loss,
                                                         float* __restrict__ out) {
    const int tid = threadIdx.x;
    const f32x4* rl4 = reinterpret_cast<const f32x4*>(row_loss);
    float acc = 0.f;
    for (int i = tid; i < N_ROWS / 4; i += 256) {
        f32x4 v = rl4[i];
        acc += v.x + v.y + v.z + v.w;
    }
    #pragma unroll
    for (int off = 32; off > 0; off >>= 1) acc += __shfl_down(acc, off, 64);
    __shared__ float sh[4];
    if ((tid & 63) == 0) sh[tid >> 6] = acc;
    __syncthreads();
    if (tid == 0) out[0] = (sh[0] + sh[1] + sh[2] + sh[3]) / (float)N_ROWS;
}

extern "C" void kernel_launch(void* const* d_in, const int* in_sizes, int n_in,
                              void* d_out, int out_size, void* d_ws, size_t ws_size,
                              hipStream_t stream) {
    const float* input  = (const float*)d_in[0];
    const float* target = (const float*)d_in[1];
    float* out      = (float*)d_out;
    float* row_loss = (float*)d_ws;  // 8192 floats = 32 KB scratch

    sce_row_kernel<<<N_ROWS, 256, 0, stream>>>(input, target, row_loss);
    sce_reduce_kernel<<<1, 256, 0, stream>>>(row_loss, out);
}